// Round 1
// baseline (494.424 us; speedup 1.0000x reference)
//
#include <hip/hip_runtime.h>
#include <hip/hip_bf16.h>

#define NB 4
#define CIN 128
#define NN 4096
#define DD 16
#define GG 4
#define EPSGN 1e-5f

// ---------------- workspace layout (floats) ----------------
// q       : 0        size B*N*16   layout [b][n][d]
// kT      : 262144   size B*N*16   layout [b][m][d]
// vT      : 524288   size B*N*16   layout [b][m][d]
// rowinv  : 786432   size B*N
// vscaled : 802816   size B*N*16   layout [b][m][d]   (v * colinv)
// t       : 1064960  size B*N*16   layout [b][n][o]
// gnstat  : 1327104  size B*G*2    (mean, rsig)
// total 1327136 floats = 5.31 MB

static __device__ __forceinline__ int waveid() {
    return __builtin_amdgcn_readfirstlane((int)(threadIdx.x >> 6));
}

// K1: 1x1 convs + positional terms -> q, kT, vT
__global__ __launch_bounds__(256) void k_qkv(
    const float* __restrict__ x_q, const float* __restrict__ x_kv,
    const float* __restrict__ xyz_q, const float* __restrict__ xyz_kv,
    const float* __restrict__ w_qk, const float* __restrict__ w_v,
    const float* __restrict__ b_v, const float* __restrict__ w_pos_q,
    const float* __restrict__ w_pos_kv,
    float* __restrict__ q, float* __restrict__ kT, float* __restrict__ vT)
{
    int gid = blockIdx.x * 256 + threadIdx.x;       // b*NN + n
    int b = gid >> 12;
    int n = gid & (NN - 1);
    const float* xq = x_q  + (size_t)b * CIN * NN + n;
    const float* xk = x_kv + (size_t)b * CIN * NN + n;

    float aq[DD], ak[DD], av[DD];
#pragma unroll
    for (int d = 0; d < DD; ++d) { aq[d] = 0.f; ak[d] = 0.f; av[d] = 0.f; }

    for (int c = 0; c < CIN; ++c) {
        float vq = xq[(size_t)c * NN];
        float vk = xk[(size_t)c * NN];
#pragma unroll
        for (int d = 0; d < DD; ++d) {
            float wq = w_qk[d * CIN + c];        // uniform -> scalar load
            aq[d] = fmaf(wq, vq, aq[d]);
            ak[d] = fmaf(wq, vk, ak[d]);
            av[d] = fmaf(w_v[d * CIN + c], vk, av[d]);
        }
    }

    float pq0 = xyz_q[((size_t)b * 3 + 0) * NN + n];
    float pq1 = xyz_q[((size_t)b * 3 + 1) * NN + n];
    float pq2 = xyz_q[((size_t)b * 3 + 2) * NN + n];
    float pk0 = xyz_kv[((size_t)b * 3 + 0) * NN + n];
    float pk1 = xyz_kv[((size_t)b * 3 + 1) * NN + n];
    float pk2 = xyz_kv[((size_t)b * 3 + 2) * NN + n];

    size_t base = (size_t)gid * DD;
#pragma unroll
    for (int d = 0; d < DD; ++d) {
        float posq = w_pos_q[d * 3 + 0] * pq0 + w_pos_q[d * 3 + 1] * pq1 + w_pos_q[d * 3 + 2] * pq2;
        float posk = w_pos_kv[d * 3 + 0] * pk0 + w_pos_kv[d * 3 + 1] * pk1 + w_pos_kv[d * 3 + 2] * pk2;
        q[base + d]  = aq[d] + posq;
        kT[base + d] = ak[d] + posk;
        vT[base + d] = av[d] + b_v[d] + posk;
    }
}

// K2a: rowinv[b][n] = 1 / sum_m exp(q[n].k[m])
// grid (NN/64, NB), block 512 (8 waves). lane <-> row, wave <-> m-split.
__global__ __launch_bounds__(512) void k_rowsum(
    const float* __restrict__ q, const float* __restrict__ kT,
    float* __restrict__ rowinv)
{
    __shared__ float part[8 * 64];
    int lane = threadIdx.x & 63;
    int w = waveid();
    int b = blockIdx.y;
    int r = blockIdx.x * 64 + lane;
    const float* qrow = q + ((size_t)b * NN + r) * DD;
    float qr[DD];
#pragma unroll
    for (int d = 0; d < DD; ++d) qr[d] = qrow[d];

    const float* kbase = kT + (size_t)b * NN * DD;
    float psum = 0.f;
    for (int m = w * 512; m < w * 512 + 512; ++m) {
        const float* kv = kbase + (size_t)m * DD;   // uniform -> scalar loads
        float e = 0.f;
#pragma unroll
        for (int d = 0; d < DD; ++d) e = fmaf(kv[d], qr[d], e);
        psum += __expf(e);
    }
    part[w * 64 + lane] = psum;
    __syncthreads();
    if (threadIdx.x < 64) {
        float s = 0.f;
#pragma unroll
        for (int ww = 0; ww < 8; ++ww) s += part[ww * 64 + lane];
        rowinv[(size_t)b * NN + r] = 1.0f / s;
    }
}

// K2b: colsum over queries, then vscaled[m][d] = vT[m][d] / (1e-9 + colsum[m])
// grid (NN/64, NB), block 512. lane <-> column, wave <-> n-split.
__global__ __launch_bounds__(512) void k_colsum_vscale(
    const float* __restrict__ q, const float* __restrict__ kT,
    const float* __restrict__ vT, const float* __restrict__ rowinv,
    float* __restrict__ vscaled)
{
    __shared__ float part[8 * 64];
    int lane = threadIdx.x & 63;
    int w = waveid();
    int b = blockIdx.y;
    int m = blockIdx.x * 64 + lane;
    const float* kcol = kT + ((size_t)b * NN + m) * DD;
    float kr[DD];
#pragma unroll
    for (int d = 0; d < DD; ++d) kr[d] = kcol[d];

    const float* qbase = q + (size_t)b * NN * DD;
    const float* rinv  = rowinv + (size_t)b * NN;
    float csum = 0.f;
    for (int n = w * 512; n < w * 512 + 512; ++n) {
        const float* qv = qbase + (size_t)n * DD;   // uniform -> scalar loads
        float e = 0.f;
#pragma unroll
        for (int d = 0; d < DD; ++d) e = fmaf(qv[d], kr[d], e);
        csum += __expf(e) * rinv[n];
    }
    part[w * 64 + lane] = csum;
    __syncthreads();
    if (threadIdx.x < 64) {
        float s = 0.f;
#pragma unroll
        for (int ww = 0; ww < 8; ++ww) s += part[ww * 64 + lane];
        float cinv = 1.0f / (1e-9f + s);
        const float* vcol = vT + ((size_t)b * NN + m) * DD;
        float* vs = vscaled + ((size_t)b * NN + m) * DD;
#pragma unroll
        for (int d = 0; d < DD; ++d) vs[d] = vcol[d] * cinv;
    }
}

// K3: x_r[n][d] = sum_m exp(q[n].k[m]) * rowinv[n] * vscaled[m][d]
//     then t[b][n][o] = b_t[o] + sum_d w_t[o][d]*(q[n][d]-x_r[n][d])
// grid (NN/64, NB), block 512. lane <-> row, wave <-> m-split, LDS combine.
__global__ __launch_bounds__(512) void k_xr_t(
    const float* __restrict__ q, const float* __restrict__ kT,
    const float* __restrict__ vscaled, const float* __restrict__ rowinv,
    const float* __restrict__ w_t, const float* __restrict__ b_t,
    float* __restrict__ t_out)
{
    __shared__ float part[8][64][17];   // padded: stride 17 avoids bank conflicts
    int lane = threadIdx.x & 63;
    int w = waveid();
    int b = blockIdx.y;
    int r = blockIdx.x * 64 + lane;

    const float* qrow = q + ((size_t)b * NN + r) * DD;
    float qr[DD];
#pragma unroll
    for (int d = 0; d < DD; ++d) qr[d] = qrow[d];
    float ri = rowinv[(size_t)b * NN + r];

    const float* kbase = kT + (size_t)b * NN * DD;
    const float* vbase = vscaled + (size_t)b * NN * DD;

    float acc[DD];
#pragma unroll
    for (int d = 0; d < DD; ++d) acc[d] = 0.f;

    for (int m = w * 512; m < w * 512 + 512; ++m) {
        const float* kv = kbase + (size_t)m * DD;   // uniform -> scalar
        const float* vv = vbase + (size_t)m * DD;   // uniform -> scalar
        float e = 0.f;
#pragma unroll
        for (int d = 0; d < DD; ++d) e = fmaf(kv[d], qr[d], e);
        float p = __expf(e) * ri;
#pragma unroll
        for (int d = 0; d < DD; ++d) acc[d] = fmaf(p, vv[d], acc[d]);
    }
#pragma unroll
    for (int d = 0; d < DD; ++d) part[w][lane][d] = acc[d];
    __syncthreads();

    if (threadIdx.x < 64) {
        float diff[DD];
#pragma unroll
        for (int d = 0; d < DD; ++d) {
            float s = 0.f;
#pragma unroll
            for (int ww = 0; ww < 8; ++ww) s += part[ww][lane][d];
            diff[d] = qr[d] - s;
        }
        float* tb = t_out + ((size_t)b * NN + r) * DD;
#pragma unroll
        for (int o = 0; o < DD; ++o) {
            float s = b_t[o];
#pragma unroll
            for (int d = 0; d < DD; ++d) s = fmaf(w_t[o * DD + d], diff[d], s);
            tb[o] = s;
        }
    }
}

// K4: GroupNorm statistics per (b, group): mean and rsqrt(var+eps)
__global__ __launch_bounds__(256) void k_gnstat(
    const float* __restrict__ t, float* __restrict__ gnstat)
{
    int bg = blockIdx.x;
    int b = bg >> 2, g = bg & 3;
    float s = 0.f, sq = 0.f;
    for (int i = threadIdx.x; i < NN * 4; i += 256) {
        int n = i >> 2, oo = (i & 3) + g * 4;
        float v = t[((size_t)b * NN + n) * DD + oo];
        s += v; sq += v * v;
    }
    __shared__ float ls[256], lq[256];
    ls[threadIdx.x] = s; lq[threadIdx.x] = sq;
    __syncthreads();
    for (int st = 128; st > 0; st >>= 1) {
        if (threadIdx.x < st) {
            ls[threadIdx.x] += ls[threadIdx.x + st];
            lq[threadIdx.x] += lq[threadIdx.x + st];
        }
        __syncthreads();
    }
    if (threadIdx.x == 0) {
        float inv = 1.0f / (float)(NN * 4);
        float mean = ls[0] * inv;
        float var = lq[0] * inv - mean * mean;
        gnstat[bg * 2 + 0] = mean;
        gnstat[bg * 2 + 1] = rsqrtf(var + EPSGN);
    }
}

// K5: out[b][o][n] = q[b][n][o] + relu(gn(t))
__global__ __launch_bounds__(256) void k_out(
    const float* __restrict__ q, const float* __restrict__ t,
    const float* __restrict__ gnstat, const float* __restrict__ gamma,
    const float* __restrict__ beta, float* __restrict__ out)
{
    int gid = blockIdx.x * 256 + threadIdx.x;   // b*NN + n
    int b = gid >> 12;
    int n = gid & (NN - 1);
    const float* qv = q + (size_t)gid * DD;
    const float* tv = t + (size_t)gid * DD;
#pragma unroll
    for (int o = 0; o < DD; ++o) {
        int g = o >> 2;
        float mean = gnstat[(b * GG + g) * 2 + 0];
        float rsig = gnstat[(b * GG + g) * 2 + 1];
        float rv = (tv[o] - mean) * rsig * gamma[o] + beta[o];
        rv = fmaxf(rv, 0.f);
        out[((size_t)b * DD + o) * NN + n] = qv[o] + rv;
    }
}

extern "C" void kernel_launch(void* const* d_in, const int* in_sizes, int n_in,
                              void* d_out, int out_size, void* d_ws, size_t ws_size,
                              hipStream_t stream)
{
    const float* x_q      = (const float*)d_in[0];
    const float* x_kv     = (const float*)d_in[1];
    const float* xyz_q    = (const float*)d_in[2];
    const float* xyz_kv   = (const float*)d_in[3];
    const float* w_qk     = (const float*)d_in[4];
    const float* w_v      = (const float*)d_in[5];
    const float* b_v      = (const float*)d_in[6];
    const float* w_t      = (const float*)d_in[7];
    const float* b_t      = (const float*)d_in[8];
    const float* gamma    = (const float*)d_in[9];
    const float* beta     = (const float*)d_in[10];
    const float* w_pos_q  = (const float*)d_in[11];
    const float* w_pos_kv = (const float*)d_in[12];

    float* ws = (float*)d_ws;
    float* q       = ws;
    float* kT      = ws + 262144;
    float* vT      = ws + 524288;
    float* rowinv  = ws + 786432;
    float* vscaled = ws + 802816;
    float* t       = ws + 1064960;
    float* gnstat  = ws + 1327104;
    float* out     = (float*)d_out;

    k_qkv<<<dim3(NB * NN / 256), 256, 0, stream>>>(
        x_q, x_kv, xyz_q, xyz_kv, w_qk, w_v, b_v, w_pos_q, w_pos_kv, q, kT, vT);

    dim3 g2(NN / 64, NB);
    k_rowsum<<<g2, 512, 0, stream>>>(q, kT, rowinv);
    k_colsum_vscale<<<g2, 512, 0, stream>>>(q, kT, vT, rowinv, vscaled);
    k_xr_t<<<g2, 512, 0, stream>>>(q, kT, vscaled, rowinv, w_t, b_t, t);
    k_gnstat<<<dim3(NB * GG), 256, 0, stream>>>(t, gnstat);
    k_out<<<dim3(NB * NN / 256), 256, 0, stream>>>(q, t, gnstat, gamma, beta, out);
}